// Round 4
// baseline (399.869 us; speedup 1.0000x reference)
//
#include <hip/hip_runtime.h>
#include <math.h>

// Problem constants (fixed by the reference)
#define NN 131072
#define KK 1024
#define DD 64
#define GAMMA 0.99f
#define ALPHA 1e-9f
#define BETA 0.25f

typedef float f32x4 __attribute__((ext_vector_type(4)));
typedef short bf16x8 __attribute__((ext_vector_type(8)));

__device__ __constant__ float OMG = (float)(1.0 - 0.99);

// split fp32 -> hi (truncated bf16) + lo (RNE bf16 of residual)
__device__ __forceinline__ void split_bf16(float v, unsigned short& h, unsigned short& l) {
    unsigned int b = __float_as_uint(v);
    unsigned int hb = b & 0xFFFF0000u;
    h = (unsigned short)(hb >> 16);
    float r = v - __uint_as_float(hb);
    unsigned int lb = __float_as_uint(r);
    lb += 0x7FFFu + ((lb >> 16) & 1u);
    l = (unsigned short)(lb >> 16);
}

// ---------------------------------------------------------------------------
// Prep: build E B-fragments in MFMA layout (hi/lo split) + esq.
// ---------------------------------------------------------------------------
__global__ __launch_bounds__(64)
void vq_prep(const float* __restrict__ E, float4* __restrict__ Efrag,
             float* __restrict__ esq) {
    int nt = blockIdx.x;
    int l = threadIdx.x;
    int n = nt * 16 + (l & 15);
    int kb = (l >> 4) * 8;
    float ss = 0.f;
    #pragma unroll
    for (int ks = 0; ks < 2; ++ks) {
        const float4* xp = (const float4*)(E + (size_t)n * DD + ks * 32 + kb);
        float4 a = xp[0], b = xp[1];
        float v[8] = {a.x, a.y, a.z, a.w, b.x, b.y, b.z, b.w};
        union { float4 f; unsigned short u[8]; } H, L;
        #pragma unroll
        for (int j = 0; j < 8; ++j) {
            unsigned short hh, ll;
            split_bf16(v[j], hh, ll);
            H.u[j] = hh; L.u[j] = ll;
            ss = fmaf(v[j], v[j], ss);
        }
        int fid = nt * 4 + ks * 2;
        Efrag[(size_t)(fid + 0) * 64 + l] = H.f;
        Efrag[(size_t)(fid + 1) * 64 + l] = L.f;
    }
    ss += __shfl_xor(ss, 16, 64);
    ss += __shfl_xor(ss, 32, 64);
    if (l < 16) esq[nt * 16 + l] = ss;
}

// ---------------------------------------------------------------------------
// Main: split-bf16 MFMA distance GEMM + argmin + light epilogue.
// Epilogue: Z, exact min_dist, loss partials, and ONE scalar atomic per row
// (cursor[bi]++) + row-index scatter into rowlist buckets. No per-lane
// sums atomics (fallback only on bucket overflow).
// ---------------------------------------------------------------------------
#define BM 128

__global__ __launch_bounds__(256, 4)
void vq_main(const float* __restrict__ X, const float* __restrict__ E,
             const float4* __restrict__ Efrag, const float* __restrict__ esq,
             float* __restrict__ argf, float* __restrict__ mind,
             float* __restrict__ Z, int* __restrict__ cursor,
             int* __restrict__ rowlist, float* __restrict__ sumsFB,
             float* __restrict__ loss_part, int cap) {
    __shared__ float redv[256];
    __shared__ int redi[256];
    __shared__ int bidx[128];

    int tid = threadIdx.x;
    int lane = tid & 63, w = tid >> 6;
    int rg = w & 1, cg = w >> 1;
    int lc = lane & 15, lq = lane >> 4;

    size_t R0 = (size_t)blockIdx.x * BM + rg * 64;

    // A fragments: 4 m-tiles x 2 k-steps, hi+lo
    bf16x8 ah[4][2], al[4][2];
    #pragma unroll
    for (int mt = 0; mt < 4; ++mt) {
        #pragma unroll
        for (int ks = 0; ks < 2; ++ks) {
            const float4* xp =
                (const float4*)(X + (R0 + mt * 16 + lc) * DD + ks * 32 + lq * 8);
            float4 x0 = xp[0], x1 = xp[1];
            float v[8] = {x0.x, x0.y, x0.z, x0.w, x1.x, x1.y, x1.z, x1.w};
            union { bf16x8 s; unsigned short u[8]; } H, L;
            #pragma unroll
            for (int j = 0; j < 8; ++j) {
                unsigned short hh, ll;
                split_bf16(v[j], hh, ll);
                H.u[j] = hh; L.u[j] = ll;
            }
            ah[mt][ks] = H.s;
            al[mt][ks] = L.s;
        }
    }

    float bestv[4][4];
    int besti[4][4];
    #pragma unroll
    for (int mt = 0; mt < 4; ++mt)
        #pragma unroll
        for (int r = 0; r < 4; ++r) { bestv[mt][r] = 3.402823466e38f; besti[mt][r] = 0; }

    const float4* bp = Efrag + (size_t)(cg * 32) * 256 + lane;
    const float* ep = esq + cg * 512 + lc;

    float4 nb0 = bp[0], nb1 = bp[64], nb2 = bp[128], nb3 = bp[192];
    float en = ep[0];

    #pragma unroll 2
    for (int nt = 0; nt < 32; ++nt) {
        float4 cb0 = nb0, cb1 = nb1, cb2 = nb2, cb3 = nb3;
        float ec = en;
        if (nt < 31) {
            const float4* q = bp + (size_t)(nt + 1) * 256;
            nb0 = q[0]; nb1 = q[64]; nb2 = q[128]; nb3 = q[192];
            en = ep[(nt + 1) * 16];
        }
        union { float4 f; bf16x8 s; } u0, u1, u2, u3;
        u0.f = cb0; u1.f = cb1; u2.f = cb2; u3.f = cb3;
        bf16x8 bh0 = u0.s, bl0 = u1.s, bh1 = u2.s, bl1 = u3.s;

        f32x4 acc[4];
        #pragma unroll
        for (int mt = 0; mt < 4; ++mt) acc[mt] = (f32x4){0.f, 0.f, 0.f, 0.f};

        #pragma unroll
        for (int mt = 0; mt < 4; ++mt)
            acc[mt] = __builtin_amdgcn_mfma_f32_16x16x32_bf16(ah[mt][0], bh0, acc[mt], 0, 0, 0);
        #pragma unroll
        for (int mt = 0; mt < 4; ++mt)
            acc[mt] = __builtin_amdgcn_mfma_f32_16x16x32_bf16(ah[mt][1], bh1, acc[mt], 0, 0, 0);
        #pragma unroll
        for (int mt = 0; mt < 4; ++mt)
            acc[mt] = __builtin_amdgcn_mfma_f32_16x16x32_bf16(ah[mt][0], bl0, acc[mt], 0, 0, 0);
        #pragma unroll
        for (int mt = 0; mt < 4; ++mt)
            acc[mt] = __builtin_amdgcn_mfma_f32_16x16x32_bf16(ah[mt][1], bl1, acc[mt], 0, 0, 0);
        #pragma unroll
        for (int mt = 0; mt < 4; ++mt)
            acc[mt] = __builtin_amdgcn_mfma_f32_16x16x32_bf16(al[mt][0], bh0, acc[mt], 0, 0, 0);
        #pragma unroll
        for (int mt = 0; mt < 4; ++mt)
            acc[mt] = __builtin_amdgcn_mfma_f32_16x16x32_bf16(al[mt][1], bh1, acc[mt], 0, 0, 0);

        int n = cg * 512 + nt * 16 + lc;
        #pragma unroll
        for (int mt = 0; mt < 4; ++mt) {
            #pragma unroll
            for (int r = 0; r < 4; ++r) {
                float sc = fmaf(-2.f, acc[mt][r], ec);
                if (sc < bestv[mt][r]) { bestv[mt][r] = sc; besti[mt][r] = n; }
            }
        }
    }

    // reduce across the 16 lanes holding one row
    #pragma unroll
    for (int off = 1; off <= 8; off <<= 1) {
        #pragma unroll
        for (int mt = 0; mt < 4; ++mt) {
            #pragma unroll
            for (int r = 0; r < 4; ++r) {
                float ov = __shfl_xor(bestv[mt][r], off, 64);
                int oi = __shfl_xor(besti[mt][r], off, 64);
                if (ov < bestv[mt][r] || (ov == bestv[mt][r] && oi < besti[mt][r])) {
                    bestv[mt][r] = ov; besti[mt][r] = oi;
                }
            }
        }
    }
    if (lc == 0) {
        #pragma unroll
        for (int mt = 0; mt < 4; ++mt)
            #pragma unroll
            for (int r = 0; r < 4; ++r) {
                int row = rg * 64 + mt * 16 + lq * 4 + r;
                redv[row * 2 + cg] = bestv[mt][r];
                redi[row * 2 + cg] = besti[mt][r];
            }
    }
    __syncthreads();
    if (tid < 128) {
        float v0 = redv[tid * 2], v1 = redv[tid * 2 + 1];
        int i0 = redi[tid * 2], i1 = redi[tid * 2 + 1];
        bidx[tid] = (v1 < v0 || (v1 == v0 && i1 < i0)) ? i1 : i0;
    }
    __syncthreads();

    // light epilogue: Z, exact min_dist, loss, cursor++ + row scatter
    float lsum = 0.f;
    #pragma unroll 4
    for (int it = 0; it < 32; ++it) {
        int row = w * 32 + it;
        int bi = bidx[row];
        size_t grow = (size_t)blockIdx.x * BM + row;
        float x = X[grow * DD + lane];
        float e = E[(size_t)bi * DD + lane];
        Z[grow * DD + lane] = x + (e - x);
        float d = x - e;
        float s = d * d;
        #pragma unroll
        for (int m = 32; m; m >>= 1) s += __shfl_xor(s, m, 64);
        int pos = 0;
        if (lane == 0) {
            pos = atomicAdd(&cursor[bi], 1);
            argf[grow] = (float)bi;
            mind[grow] = s;   // exact fp32 sum((x-e)^2)
        }
        pos = __shfl(pos, 0, 64);
        if (pos < cap) {
            if (lane == 0) rowlist[(size_t)bi * cap + pos] = (int)grow;
        } else {
            atomicAdd(&sumsFB[(size_t)bi * DD + lane], x);  // overflow fallback
        }
        lsum += s;
    }
    if (lane == 0) atomicAdd(&loss_part[(blockIdx.x * 4 + w) & 1023], lsum);
}

// ---------------------------------------------------------------------------
// cs (normalized cluster sizes) + loss finalize — single block.
// ---------------------------------------------------------------------------
__global__ __launch_bounds__(1024)
void vq_cs(const float* __restrict__ cluster_sizes, const int* __restrict__ cursor,
           const float* __restrict__ loss_part, float* __restrict__ out_cs,
           float* __restrict__ out_loss) {
    __shared__ float red[1024];
    int k = threadIdx.x;
    float csr = GAMMA * cluster_sizes[k] + OMG * (float)cursor[k];
    red[k] = csr;
    __syncthreads();
    for (int off = 512; off; off >>= 1) {
        if (k < off) red[k] += red[k + off];
        __syncthreads();
    }
    float total = red[0];
    __syncthreads();
    red[k] = loss_part[k];
    __syncthreads();
    for (int off = 512; off; off >>= 1) {
        if (k < off) red[k] += red[k + off];
        __syncthreads();
    }
    if (k == 0) out_loss[0] = BETA * (red[0] / (float)NN);

    float denom = 1.0f + (ALPHA * (float)KK) / total;
    out_cs[k] = (csr + ALPHA) / denom;
}

// ---------------------------------------------------------------------------
// Segment sum (atomic-free) fused with ma / E_new. One block per code.
// ---------------------------------------------------------------------------
__global__ __launch_bounds__(256)
void vq_sum_ema(const float* __restrict__ X, const int* __restrict__ rowlist,
                const int* __restrict__ cursor, const float* __restrict__ sumsFB,
                const float* __restrict__ cs, const float* __restrict__ mavg,
                float* __restrict__ o_ma, float* __restrict__ o_enew, int cap) {
    __shared__ float part[4][64];
    int k = blockIdx.x;
    int lane = threadIdx.x & 63, w = threadIdx.x >> 6;
    int cnt = cursor[k];
    int nr = cnt < cap ? cnt : cap;
    const int* rl = rowlist + (size_t)k * cap;
    float acc = 0.f;
    #pragma unroll 2
    for (int i = w; i < nr; i += 4) {
        int r = rl[i];
        acc += X[(size_t)r * DD + lane];
    }
    part[w][lane] = acc;
    __syncthreads();
    if (w == 0) {
        float s = part[0][lane] + part[1][lane] + part[2][lane] + part[3][lane]
                + sumsFB[(size_t)k * DD + lane];
        float ma = GAMMA * mavg[(size_t)k * DD + lane] + OMG * s;
        o_ma[(size_t)k * DD + lane] = ma;
        o_enew[(size_t)k * DD + lane] = ma / cs[k];
    }
}

// ---------------------------------------------------------------------------
extern "C" void kernel_launch(void* const* d_in, const int* in_sizes, int n_in,
                              void* d_out, int out_size, void* d_ws, size_t ws_size,
                              hipStream_t stream) {
    const float* X = (const float*)d_in[0];
    const float* E = (const float*)d_in[1];
    const float* cluster_sizes = (const float*)d_in[2];
    const float* moving_avg = (const float*)d_in[3];

    // Output layout: Z[N*D], loss[1], argmins[N], min_dist[N],
    //                E_new[K*D], cs[K], ma[K*D]
    float* out = (float*)d_out;
    float* o_Z = out;
    float* o_loss = o_Z + (size_t)NN * DD;
    float* o_arg = o_loss + 1;
    float* o_mind = o_arg + NN;
    float* o_enew = o_mind + NN;
    float* o_cs = o_enew + (size_t)KK * DD;
    float* o_ma = o_cs + KK;

    // Workspace (4B units):
    // [cursor 1024 i32][loss_part 1024 f][sumsFB 65536 f][esq 1024 f]
    // [Efrag 65536 f][rowlist K*cap i32]
    int* cursor = (int*)d_ws;
    float* loss_part = (float*)d_ws + 1024;
    float* sumsFB = loss_part + 1024;
    float* esq = sumsFB + (size_t)KK * DD;
    float4* Efrag = (float4*)(esq + KK);
    int* rowlist = (int*)(esq + KK + (size_t)KK * DD);

    size_t base_bytes = (size_t)(1024 + 1024 + KK * DD + KK + KK * DD) * 4;
    long cap_l = ((long)ws_size - (long)base_bytes) / (long)(KK * sizeof(int));
    int cap = cap_l < 0 ? 0 : (cap_l > 1024 ? 1024 : (int)cap_l);

    // zero cursor + loss_part + sumsFB (contiguous prefix)
    hipMemsetAsync(d_ws, 0, (size_t)(1024 + 1024 + KK * DD) * 4, stream);

    vq_prep<<<KK / 16, 64, 0, stream>>>(E, Efrag, esq);
    vq_main<<<NN / BM, 256, 0, stream>>>(X, E, Efrag, esq, o_arg, o_mind, o_Z,
                                         cursor, rowlist, sumsFB, loss_part, cap);
    vq_cs<<<1, 1024, 0, stream>>>(cluster_sizes, cursor, loss_part, o_cs, o_loss);
    vq_sum_ema<<<KK, 256, 0, stream>>>(X, rowlist, cursor, sumsFB, o_cs,
                                       moving_avg, o_ma, o_enew, cap);
}

// Round 5
// 285.087 us; speedup vs baseline: 1.4026x; 1.4026x over previous
//
#include <hip/hip_runtime.h>
#include <math.h>

// Problem constants (fixed by the reference)
#define NN 131072
#define KK 1024
#define DD 64
#define GAMMA 0.99f
#define ALPHA 1e-9f
#define BETA 0.25f

typedef float f32x4 __attribute__((ext_vector_type(4)));
typedef short bf16x8 __attribute__((ext_vector_type(8)));

__device__ __constant__ float OMG = (float)(1.0 - 0.99);

// split fp32 -> hi (truncated bf16) + lo (RNE bf16 of residual)
__device__ __forceinline__ void split_bf16(float v, unsigned short& h, unsigned short& l) {
    unsigned int b = __float_as_uint(v);
    unsigned int hb = b & 0xFFFF0000u;
    h = (unsigned short)(hb >> 16);
    float r = v - __uint_as_float(hb);
    unsigned int lb = __float_as_uint(r);
    lb += 0x7FFFu + ((lb >> 16) & 1u);
    l = (unsigned short)(lb >> 16);
}

// ---------------------------------------------------------------------------
// Prep: build E B-fragments in MFMA layout (hi/lo split) + esq.
// ---------------------------------------------------------------------------
__global__ __launch_bounds__(64)
void vq_prep(const float* __restrict__ E, float4* __restrict__ Efrag,
             float* __restrict__ esq) {
    int nt = blockIdx.x;
    int l = threadIdx.x;
    int n = nt * 16 + (l & 15);
    int kb = (l >> 4) * 8;
    float ss = 0.f;
    #pragma unroll
    for (int ks = 0; ks < 2; ++ks) {
        const float4* xp = (const float4*)(E + (size_t)n * DD + ks * 32 + kb);
        float4 a = xp[0], b = xp[1];
        float v[8] = {a.x, a.y, a.z, a.w, b.x, b.y, b.z, b.w};
        union { float4 f; unsigned short u[8]; } H, L;
        #pragma unroll
        for (int j = 0; j < 8; ++j) {
            unsigned short hh, ll;
            split_bf16(v[j], hh, ll);
            H.u[j] = hh; L.u[j] = ll;
            ss = fmaf(v[j], v[j], ss);
        }
        int fid = nt * 4 + ks * 2;
        Efrag[(size_t)(fid + 0) * 64 + l] = H.f;
        Efrag[(size_t)(fid + 1) * 64 + l] = L.f;
    }
    ss += __shfl_xor(ss, 16, 64);
    ss += __shfl_xor(ss, 32, 64);
    if (l < 16) esq[nt * 16 + l] = ss;
}

// ---------------------------------------------------------------------------
// Main: split-bf16 MFMA distance GEMM + argmin + light epilogue.
// __launch_bounds__(256,2): the kernel needs ~100+ VGPRs (64 for A frags);
// (256,4) forces spill of the A fragments -> 230 MB scratch traffic (R4).
// ---------------------------------------------------------------------------
#define BM 128

__global__ __launch_bounds__(256, 2)
void vq_main(const float* __restrict__ X, const float* __restrict__ E,
             const float4* __restrict__ Efrag, const float* __restrict__ esq,
             float* __restrict__ argf, float* __restrict__ mind,
             float* __restrict__ Z, int* __restrict__ cursor,
             int* __restrict__ rowlist, float* __restrict__ sumsFB,
             float* __restrict__ loss_part, int cap) {
    __shared__ float redv[256];
    __shared__ int redi[256];
    __shared__ int bidx[128];

    int tid = threadIdx.x;
    int lane = tid & 63, w = tid >> 6;
    int rg = w & 1, cg = w >> 1;
    int lc = lane & 15, lq = lane >> 4;

    size_t R0 = (size_t)blockIdx.x * BM + rg * 64;

    // A fragments: 4 m-tiles x 2 k-steps, hi+lo (64 VGPRs)
    bf16x8 ah[4][2], al[4][2];
    #pragma unroll
    for (int mt = 0; mt < 4; ++mt) {
        #pragma unroll
        for (int ks = 0; ks < 2; ++ks) {
            const float4* xp =
                (const float4*)(X + (R0 + mt * 16 + lc) * DD + ks * 32 + lq * 8);
            float4 x0 = xp[0], x1 = xp[1];
            float v[8] = {x0.x, x0.y, x0.z, x0.w, x1.x, x1.y, x1.z, x1.w};
            union { bf16x8 s; unsigned short u[8]; } H, L;
            #pragma unroll
            for (int j = 0; j < 8; ++j) {
                unsigned short hh, ll;
                split_bf16(v[j], hh, ll);
                H.u[j] = hh; L.u[j] = ll;
            }
            ah[mt][ks] = H.s;
            al[mt][ks] = L.s;
        }
    }

    float bestv[4][4];
    int besti[4][4];
    #pragma unroll
    for (int mt = 0; mt < 4; ++mt)
        #pragma unroll
        for (int r = 0; r < 4; ++r) { bestv[mt][r] = 3.402823466e38f; besti[mt][r] = 0; }

    const float4* bp = Efrag + (size_t)(cg * 32) * 256 + lane;
    const float* ep = esq + cg * 512 + lc;

    float4 nb0 = bp[0], nb1 = bp[64], nb2 = bp[128], nb3 = bp[192];
    float en = ep[0];

    for (int nt = 0; nt < 32; ++nt) {
        float4 cb0 = nb0, cb1 = nb1, cb2 = nb2, cb3 = nb3;
        float ec = en;
        if (nt < 31) {
            const float4* q = bp + (size_t)(nt + 1) * 256;
            nb0 = q[0]; nb1 = q[64]; nb2 = q[128]; nb3 = q[192];
            en = ep[(nt + 1) * 16];
        }
        union { float4 f; bf16x8 s; } u0, u1, u2, u3;
        u0.f = cb0; u1.f = cb1; u2.f = cb2; u3.f = cb3;
        bf16x8 bh0 = u0.s, bl0 = u1.s, bh1 = u2.s, bl1 = u3.s;

        f32x4 acc[4];
        #pragma unroll
        for (int mt = 0; mt < 4; ++mt) acc[mt] = (f32x4){0.f, 0.f, 0.f, 0.f};

        #pragma unroll
        for (int mt = 0; mt < 4; ++mt)
            acc[mt] = __builtin_amdgcn_mfma_f32_16x16x32_bf16(ah[mt][0], bh0, acc[mt], 0, 0, 0);
        #pragma unroll
        for (int mt = 0; mt < 4; ++mt)
            acc[mt] = __builtin_amdgcn_mfma_f32_16x16x32_bf16(ah[mt][1], bh1, acc[mt], 0, 0, 0);
        #pragma unroll
        for (int mt = 0; mt < 4; ++mt)
            acc[mt] = __builtin_amdgcn_mfma_f32_16x16x32_bf16(ah[mt][0], bl0, acc[mt], 0, 0, 0);
        #pragma unroll
        for (int mt = 0; mt < 4; ++mt)
            acc[mt] = __builtin_amdgcn_mfma_f32_16x16x32_bf16(ah[mt][1], bl1, acc[mt], 0, 0, 0);
        #pragma unroll
        for (int mt = 0; mt < 4; ++mt)
            acc[mt] = __builtin_amdgcn_mfma_f32_16x16x32_bf16(al[mt][0], bh0, acc[mt], 0, 0, 0);
        #pragma unroll
        for (int mt = 0; mt < 4; ++mt)
            acc[mt] = __builtin_amdgcn_mfma_f32_16x16x32_bf16(al[mt][1], bh1, acc[mt], 0, 0, 0);

        int n = cg * 512 + nt * 16 + lc;
        #pragma unroll
        for (int mt = 0; mt < 4; ++mt) {
            #pragma unroll
            for (int r = 0; r < 4; ++r) {
                float sc = fmaf(-2.f, acc[mt][r], ec);
                if (sc < bestv[mt][r]) { bestv[mt][r] = sc; besti[mt][r] = n; }
            }
        }
    }

    // reduce across the 16 lanes holding one row
    #pragma unroll
    for (int off = 1; off <= 8; off <<= 1) {
        #pragma unroll
        for (int mt = 0; mt < 4; ++mt) {
            #pragma unroll
            for (int r = 0; r < 4; ++r) {
                float ov = __shfl_xor(bestv[mt][r], off, 64);
                int oi = __shfl_xor(besti[mt][r], off, 64);
                if (ov < bestv[mt][r] || (ov == bestv[mt][r] && oi < besti[mt][r])) {
                    bestv[mt][r] = ov; besti[mt][r] = oi;
                }
            }
        }
    }
    if (lc == 0) {
        #pragma unroll
        for (int mt = 0; mt < 4; ++mt)
            #pragma unroll
            for (int r = 0; r < 4; ++r) {
                int row = rg * 64 + mt * 16 + lq * 4 + r;
                redv[row * 2 + cg] = bestv[mt][r];
                redi[row * 2 + cg] = besti[mt][r];
            }
    }
    __syncthreads();
    if (tid < 128) {
        float v0 = redv[tid * 2], v1 = redv[tid * 2 + 1];
        int i0 = redi[tid * 2], i1 = redi[tid * 2 + 1];
        bidx[tid] = (v1 < v0 || (v1 == v0 && i1 < i0)) ? i1 : i0;
    }
    __syncthreads();

    // light epilogue: Z, exact min_dist, loss, cursor++ + row scatter
    float lsum = 0.f;
    for (int it = 0; it < 32; ++it) {
        int row = w * 32 + it;
        int bi = bidx[row];
        size_t grow = (size_t)blockIdx.x * BM + row;
        float x = X[grow * DD + lane];
        float e = E[(size_t)bi * DD + lane];
        Z[grow * DD + lane] = x + (e - x);
        float d = x - e;
        float s = d * d;
        #pragma unroll
        for (int m = 32; m; m >>= 1) s += __shfl_xor(s, m, 64);
        int pos = 0;
        if (lane == 0) {
            pos = atomicAdd(&cursor[bi], 1);
            argf[grow] = (float)bi;
            mind[grow] = s;   // exact fp32 sum((x-e)^2)
        }
        pos = __shfl(pos, 0, 64);
        if (pos < cap) {
            if (lane == 0) rowlist[(size_t)bi * cap + pos] = (int)grow;
        } else {
            atomicAdd(&sumsFB[(size_t)bi * DD + lane], x);  // overflow fallback
        }
        lsum += s;
    }
    if (lane == 0) atomicAdd(&loss_part[(blockIdx.x * 4 + w) & 1023], lsum);
}

// ---------------------------------------------------------------------------
// cs (normalized cluster sizes) + loss finalize — single block.
// ---------------------------------------------------------------------------
__global__ __launch_bounds__(1024)
void vq_cs(const float* __restrict__ cluster_sizes, const int* __restrict__ cursor,
           const float* __restrict__ loss_part, float* __restrict__ out_cs,
           float* __restrict__ out_loss) {
    __shared__ float red[1024];
    int k = threadIdx.x;
    float csr = GAMMA * cluster_sizes[k] + OMG * (float)cursor[k];
    red[k] = csr;
    __syncthreads();
    for (int off = 512; off; off >>= 1) {
        if (k < off) red[k] += red[k + off];
        __syncthreads();
    }
    float total = red[0];
    __syncthreads();
    red[k] = loss_part[k];
    __syncthreads();
    for (int off = 512; off; off >>= 1) {
        if (k < off) red[k] += red[k + off];
        __syncthreads();
    }
    if (k == 0) out_loss[0] = BETA * (red[0] / (float)NN);

    float denom = 1.0f + (ALPHA * (float)KK) / total;
    out_cs[k] = (csr + ALPHA) / denom;
}

// ---------------------------------------------------------------------------
// Segment sum (atomic-free) fused with ma / E_new. One block per code.
// ---------------------------------------------------------------------------
__global__ __launch_bounds__(256)
void vq_sum_ema(const float* __restrict__ X, const int* __restrict__ rowlist,
                const int* __restrict__ cursor, const float* __restrict__ sumsFB,
                const float* __restrict__ cs, const float* __restrict__ mavg,
                float* __restrict__ o_ma, float* __restrict__ o_enew, int cap) {
    __shared__ float part[4][64];
    int k = blockIdx.x;
    int lane = threadIdx.x & 63, w = threadIdx.x >> 6;
    int cnt = cursor[k];
    int nr = cnt < cap ? cnt : cap;
    const int* rl = rowlist + (size_t)k * cap;
    float acc = 0.f;
    #pragma unroll 2
    for (int i = w; i < nr; i += 4) {
        int r = rl[i];
        acc += X[(size_t)r * DD + lane];
    }
    part[w][lane] = acc;
    __syncthreads();
    if (w == 0) {
        float s = part[0][lane] + part[1][lane] + part[2][lane] + part[3][lane]
                + sumsFB[(size_t)k * DD + lane];
        float ma = GAMMA * mavg[(size_t)k * DD + lane] + OMG * s;
        o_ma[(size_t)k * DD + lane] = ma;
        o_enew[(size_t)k * DD + lane] = ma / cs[k];
    }
}

// ---------------------------------------------------------------------------
extern "C" void kernel_launch(void* const* d_in, const int* in_sizes, int n_in,
                              void* d_out, int out_size, void* d_ws, size_t ws_size,
                              hipStream_t stream) {
    const float* X = (const float*)d_in[0];
    const float* E = (const float*)d_in[1];
    const float* cluster_sizes = (const float*)d_in[2];
    const float* moving_avg = (const float*)d_in[3];

    // Output layout: Z[N*D], loss[1], argmins[N], min_dist[N],
    //                E_new[K*D], cs[K], ma[K*D]
    float* out = (float*)d_out;
    float* o_Z = out;
    float* o_loss = o_Z + (size_t)NN * DD;
    float* o_arg = o_loss + 1;
    float* o_mind = o_arg + NN;
    float* o_enew = o_mind + NN;
    float* o_cs = o_enew + (size_t)KK * DD;
    float* o_ma = o_cs + KK;

    // Workspace (4B units):
    // [cursor 1024 i32][loss_part 1024 f][sumsFB 65536 f][esq 1024 f]
    // [Efrag 65536 f][rowlist K*cap i32]
    int* cursor = (int*)d_ws;
    float* loss_part = (float*)d_ws + 1024;
    float* sumsFB = loss_part + 1024;
    float* esq = sumsFB + (size_t)KK * DD;
    float4* Efrag = (float4*)(esq + KK);
    int* rowlist = (int*)(esq + KK + (size_t)KK * DD);

    size_t base_bytes = (size_t)(1024 + 1024 + KK * DD + KK + KK * DD) * 4;
    long cap_l = ((long)ws_size - (long)base_bytes) / (long)(KK * sizeof(int));
    int cap = cap_l < 0 ? 0 : (cap_l > 1024 ? 1024 : (int)cap_l);

    // zero cursor + loss_part + sumsFB (contiguous prefix)
    hipMemsetAsync(d_ws, 0, (size_t)(1024 + 1024 + KK * DD) * 4, stream);

    vq_prep<<<KK / 16, 64, 0, stream>>>(E, Efrag, esq);
    vq_main<<<NN / BM, 256, 0, stream>>>(X, E, Efrag, esq, o_arg, o_mind, o_Z,
                                         cursor, rowlist, sumsFB, loss_part, cap);
    vq_cs<<<1, 1024, 0, stream>>>(cluster_sizes, cursor, loss_part, o_cs, o_loss);
    vq_sum_ema<<<KK, 256, 0, stream>>>(X, rowlist, cursor, sumsFB, o_cs,
                                       moving_avg, o_ma, o_enew, cap);
}

// Round 6
// 241.327 us; speedup vs baseline: 1.6570x; 1.1813x over previous
//
#include <hip/hip_runtime.h>
#include <math.h>

// Problem constants (fixed by the reference)
#define NN 131072
#define KK 1024
#define DD 64
#define GAMMA 0.99f
#define ALPHA 1e-9f
#define BETA 0.25f

typedef float f32x4 __attribute__((ext_vector_type(4)));
typedef short bf16x8 __attribute__((ext_vector_type(8)));

__device__ __constant__ float OMG = (float)(1.0 - 0.99);

// split fp32 -> hi (truncated bf16) + lo (RNE bf16 of residual)
__device__ __forceinline__ void split_bf16(float v, unsigned short& h, unsigned short& l) {
    unsigned int b = __float_as_uint(v);
    unsigned int hb = b & 0xFFFF0000u;
    h = (unsigned short)(hb >> 16);
    float r = v - __uint_as_float(hb);
    unsigned int lb = __float_as_uint(r);
    lb += 0x7FFFu + ((lb >> 16) & 1u);
    l = (unsigned short)(lb >> 16);
}

// ---------------------------------------------------------------------------
// Prep: build E B-fragments in MFMA layout (hi/lo split) + esq.
// ---------------------------------------------------------------------------
__global__ __launch_bounds__(64)
void vq_prep(const float* __restrict__ E, float4* __restrict__ Efrag,
             float* __restrict__ esq) {
    int nt = blockIdx.x;
    int l = threadIdx.x;
    int n = nt * 16 + (l & 15);
    int kb = (l >> 4) * 8;
    float ss = 0.f;
    #pragma unroll
    for (int ks = 0; ks < 2; ++ks) {
        const float4* xp = (const float4*)(E + (size_t)n * DD + ks * 32 + kb);
        float4 a = xp[0], b = xp[1];
        float v[8] = {a.x, a.y, a.z, a.w, b.x, b.y, b.z, b.w};
        union { float4 f; unsigned short u[8]; } H, L;
        #pragma unroll
        for (int j = 0; j < 8; ++j) {
            unsigned short hh, ll;
            split_bf16(v[j], hh, ll);
            H.u[j] = hh; L.u[j] = ll;
            ss = fmaf(v[j], v[j], ss);
        }
        int fid = nt * 4 + ks * 2;
        Efrag[(size_t)(fid + 0) * 64 + l] = H.f;
        Efrag[(size_t)(fid + 1) * 64 + l] = L.f;
    }
    ss += __shfl_xor(ss, 16, 64);
    ss += __shfl_xor(ss, 32, 64);
    if (l < 16) esq[nt * 16 + l] = ss;
}

// ---------------------------------------------------------------------------
// Main: split-bf16 MFMA distance GEMM + argmin + latency-free epilogue.
// Epilogue: (B) lanes 0..31 each own one row -> 32 cursor atomics in flight
// at once (ONE wait, not 32 serialized round trips); mind/loss from
// xsq + best score (no X re-read); (C) Z loop = pure E-gather stream.
// __launch_bounds__(256,2): needs ~100 VGPRs; (256,4) spills A frags (R4).
// ---------------------------------------------------------------------------
#define BM 128

__global__ __launch_bounds__(256, 2)
void vq_main(const float* __restrict__ X, const float* __restrict__ E,
             const float4* __restrict__ Efrag, const float* __restrict__ esq,
             float* __restrict__ argf, float* __restrict__ mind,
             float* __restrict__ Z, int* __restrict__ cursor,
             int* __restrict__ rowlist, float* __restrict__ sumsFB,
             float* __restrict__ loss_part, int cap) {
    __shared__ float redv[256];
    __shared__ int redi[256];
    __shared__ int bidx[128];
    __shared__ float bsc[128];
    __shared__ float xsqs[128];
    __shared__ int fbflag[128];

    int tid = threadIdx.x;
    int lane = tid & 63, w = tid >> 6;
    int rg = w & 1, cg = w >> 1;
    int lc = lane & 15, lq = lane >> 4;

    size_t bb = (size_t)blockIdx.x * BM;
    size_t R0 = bb + rg * 64;

    // A fragments: 4 m-tiles x 2 k-steps, hi+lo (64 VGPRs) + exact xsq
    bf16x8 ah[4][2], al[4][2];
    #pragma unroll
    for (int mt = 0; mt < 4; ++mt) {
        float xq = 0.f;
        #pragma unroll
        for (int ks = 0; ks < 2; ++ks) {
            const float4* xp =
                (const float4*)(X + (R0 + mt * 16 + lc) * DD + ks * 32 + lq * 8);
            float4 x0 = xp[0], x1 = xp[1];
            float v[8] = {x0.x, x0.y, x0.z, x0.w, x1.x, x1.y, x1.z, x1.w};
            union { bf16x8 s; unsigned short u[8]; } H, L;
            #pragma unroll
            for (int j = 0; j < 8; ++j) {
                unsigned short hh, ll;
                split_bf16(v[j], hh, ll);
                H.u[j] = hh; L.u[j] = ll;
                xq = fmaf(v[j], v[j], xq);
            }
            ah[mt][ks] = H.s;
            al[mt][ks] = L.s;
        }
        // reduce xq over the 4 k-slice lanes {lc, lc+16, lc+32, lc+48}
        xq += __shfl_xor(xq, 16, 64);
        xq += __shfl_xor(xq, 32, 64);
        if (lane < 16) xsqs[rg * 64 + mt * 16 + lane] = xq;
    }

    float bestv[4][4];
    int besti[4][4];
    #pragma unroll
    for (int mt = 0; mt < 4; ++mt)
        #pragma unroll
        for (int r = 0; r < 4; ++r) { bestv[mt][r] = 3.402823466e38f; besti[mt][r] = 0; }

    const float4* bp = Efrag + (size_t)(cg * 32) * 256 + lane;
    const float* ep = esq + cg * 512 + lc;

    float4 nb0 = bp[0], nb1 = bp[64], nb2 = bp[128], nb3 = bp[192];
    float en = ep[0];

    for (int nt = 0; nt < 32; ++nt) {
        float4 cb0 = nb0, cb1 = nb1, cb2 = nb2, cb3 = nb3;
        float ec = en;
        if (nt < 31) {
            const float4* q = bp + (size_t)(nt + 1) * 256;
            nb0 = q[0]; nb1 = q[64]; nb2 = q[128]; nb3 = q[192];
            en = ep[(nt + 1) * 16];
        }
        union { float4 f; bf16x8 s; } u0, u1, u2, u3;
        u0.f = cb0; u1.f = cb1; u2.f = cb2; u3.f = cb3;
        bf16x8 bh0 = u0.s, bl0 = u1.s, bh1 = u2.s, bl1 = u3.s;

        f32x4 acc[4];
        #pragma unroll
        for (int mt = 0; mt < 4; ++mt) acc[mt] = (f32x4){0.f, 0.f, 0.f, 0.f};

        #pragma unroll
        for (int mt = 0; mt < 4; ++mt)
            acc[mt] = __builtin_amdgcn_mfma_f32_16x16x32_bf16(ah[mt][0], bh0, acc[mt], 0, 0, 0);
        #pragma unroll
        for (int mt = 0; mt < 4; ++mt)
            acc[mt] = __builtin_amdgcn_mfma_f32_16x16x32_bf16(ah[mt][1], bh1, acc[mt], 0, 0, 0);
        #pragma unroll
        for (int mt = 0; mt < 4; ++mt)
            acc[mt] = __builtin_amdgcn_mfma_f32_16x16x32_bf16(ah[mt][0], bl0, acc[mt], 0, 0, 0);
        #pragma unroll
        for (int mt = 0; mt < 4; ++mt)
            acc[mt] = __builtin_amdgcn_mfma_f32_16x16x32_bf16(ah[mt][1], bl1, acc[mt], 0, 0, 0);
        #pragma unroll
        for (int mt = 0; mt < 4; ++mt)
            acc[mt] = __builtin_amdgcn_mfma_f32_16x16x32_bf16(al[mt][0], bh0, acc[mt], 0, 0, 0);
        #pragma unroll
        for (int mt = 0; mt < 4; ++mt)
            acc[mt] = __builtin_amdgcn_mfma_f32_16x16x32_bf16(al[mt][1], bh1, acc[mt], 0, 0, 0);

        int n = cg * 512 + nt * 16 + lc;
        #pragma unroll
        for (int mt = 0; mt < 4; ++mt) {
            #pragma unroll
            for (int r = 0; r < 4; ++r) {
                float sc = fmaf(-2.f, acc[mt][r], ec);
                if (sc < bestv[mt][r]) { bestv[mt][r] = sc; besti[mt][r] = n; }
            }
        }
    }

    // reduce across the 16 lanes holding one row
    #pragma unroll
    for (int off = 1; off <= 8; off <<= 1) {
        #pragma unroll
        for (int mt = 0; mt < 4; ++mt) {
            #pragma unroll
            for (int r = 0; r < 4; ++r) {
                float ov = __shfl_xor(bestv[mt][r], off, 64);
                int oi = __shfl_xor(besti[mt][r], off, 64);
                if (ov < bestv[mt][r] || (ov == bestv[mt][r] && oi < besti[mt][r])) {
                    bestv[mt][r] = ov; besti[mt][r] = oi;
                }
            }
        }
    }
    if (lc == 0) {
        #pragma unroll
        for (int mt = 0; mt < 4; ++mt)
            #pragma unroll
            for (int r = 0; r < 4; ++r) {
                int row = rg * 64 + mt * 16 + lq * 4 + r;
                redv[row * 2 + cg] = bestv[mt][r];
                redi[row * 2 + cg] = besti[mt][r];
            }
    }
    __syncthreads();
    if (tid < 128) {
        float v0 = redv[tid * 2], v1 = redv[tid * 2 + 1];
        int i0 = redi[tid * 2], i1 = redi[tid * 2 + 1];
        int pick = (v1 < v0 || (v1 == v0 && i1 < i0));
        bidx[tid] = pick ? i1 : i0;
        bsc[tid] = pick ? v1 : v0;
    }
    __syncthreads();

    // Phase B: one row per lane (l<32) -> 32 concurrent cursor atomics/wave
    float md = 0.f;
    if (lane < 32) {
        int row = w * 32 + lane;
        int bi = bidx[row];
        size_t grow = bb + row;
        md = xsqs[row] + bsc[row];          // dist = xsq + (esq - 2*dot)
        mind[grow] = md;
        argf[grow] = (float)bi;
        int pos = atomicAdd(&cursor[bi], 1);
        if (pos < cap) {
            rowlist[(size_t)bi * cap + pos] = (int)grow;
            fbflag[row] = 0;
        } else {
            fbflag[row] = 1;                // overflow -> fallback atomics
        }
    }
    #pragma unroll
    for (int m = 32; m; m >>= 1) md += __shfl_xor(md, m, 64);
    if (lane == 0) atomicAdd(&loss_part[(blockIdx.x * 4 + w) & 1023], md);
    __syncthreads();

    // Phase C: Z = E[argmin] gather stream (no X, no atomics, no reduces)
    for (int it = 0; it < 32; ++it) {
        int row = w * 32 + it;
        int bi = bidx[row];
        size_t grow = bb + row;
        float e = E[(size_t)bi * DD + lane];
        Z[grow * DD + lane] = e;            // x + (e - x) == e to fp32 noise
        if (fbflag[row]) {
            float x = X[grow * DD + lane];
            atomicAdd(&sumsFB[(size_t)bi * DD + lane], x);
        }
    }
}

// ---------------------------------------------------------------------------
// cs (normalized cluster sizes) + loss finalize — single block.
// ---------------------------------------------------------------------------
__global__ __launch_bounds__(1024)
void vq_cs(const float* __restrict__ cluster_sizes, const int* __restrict__ cursor,
           const float* __restrict__ loss_part, float* __restrict__ out_cs,
           float* __restrict__ out_loss) {
    __shared__ float red[1024];
    int k = threadIdx.x;
    float csr = GAMMA * cluster_sizes[k] + OMG * (float)cursor[k];
    red[k] = csr;
    __syncthreads();
    for (int off = 512; off; off >>= 1) {
        if (k < off) red[k] += red[k + off];
        __syncthreads();
    }
    float total = red[0];
    __syncthreads();
    red[k] = loss_part[k];
    __syncthreads();
    for (int off = 512; off; off >>= 1) {
        if (k < off) red[k] += red[k + off];
        __syncthreads();
    }
    if (k == 0) out_loss[0] = BETA * (red[0] / (float)NN);

    float denom = 1.0f + (ALPHA * (float)KK) / total;
    out_cs[k] = (csr + ALPHA) / denom;
}

// ---------------------------------------------------------------------------
// Segment sum (atomic-free) fused with ma / E_new. One block per code.
// ---------------------------------------------------------------------------
__global__ __launch_bounds__(256)
void vq_sum_ema(const float* __restrict__ X, const int* __restrict__ rowlist,
                const int* __restrict__ cursor, const float* __restrict__ sumsFB,
                const float* __restrict__ cs, const float* __restrict__ mavg,
                float* __restrict__ o_ma, float* __restrict__ o_enew, int cap) {
    __shared__ float part[4][64];
    int k = blockIdx.x;
    int lane = threadIdx.x & 63, w = threadIdx.x >> 6;
    int cnt = cursor[k];
    int nr = cnt < cap ? cnt : cap;
    const int* rl = rowlist + (size_t)k * cap;
    float acc = 0.f;
    #pragma unroll 4
    for (int i = w; i < nr; i += 4) {
        int r = rl[i];
        acc += X[(size_t)r * DD + lane];
    }
    part[w][lane] = acc;
    __syncthreads();
    if (w == 0) {
        float s = part[0][lane] + part[1][lane] + part[2][lane] + part[3][lane]
                + sumsFB[(size_t)k * DD + lane];
        float ma = GAMMA * mavg[(size_t)k * DD + lane] + OMG * s;
        o_ma[(size_t)k * DD + lane] = ma;
        o_enew[(size_t)k * DD + lane] = ma / cs[k];
    }
}

// ---------------------------------------------------------------------------
extern "C" void kernel_launch(void* const* d_in, const int* in_sizes, int n_in,
                              void* d_out, int out_size, void* d_ws, size_t ws_size,
                              hipStream_t stream) {
    const float* X = (const float*)d_in[0];
    const float* E = (const float*)d_in[1];
    const float* cluster_sizes = (const float*)d_in[2];
    const float* moving_avg = (const float*)d_in[3];

    // Output layout: Z[N*D], loss[1], argmins[N], min_dist[N],
    //                E_new[K*D], cs[K], ma[K*D]
    float* out = (float*)d_out;
    float* o_Z = out;
    float* o_loss = o_Z + (size_t)NN * DD;
    float* o_arg = o_loss + 1;
    float* o_mind = o_arg + NN;
    float* o_enew = o_mind + NN;
    float* o_cs = o_enew + (size_t)KK * DD;
    float* o_ma = o_cs + KK;

    // Workspace (4B units):
    // [cursor 1024 i32][loss_part 1024 f][sumsFB 65536 f][esq 1024 f]
    // [Efrag 65536 f][rowlist K*cap i32]
    int* cursor = (int*)d_ws;
    float* loss_part = (float*)d_ws + 1024;
    float* sumsFB = loss_part + 1024;
    float* esq = sumsFB + (size_t)KK * DD;
    float4* Efrag = (float4*)(esq + KK);
    int* rowlist = (int*)(esq + KK + (size_t)KK * DD);

    size_t base_bytes = (size_t)(1024 + 1024 + KK * DD + KK + KK * DD) * 4;
    long cap_l = ((long)ws_size - (long)base_bytes) / (long)(KK * sizeof(int));
    int cap = cap_l < 0 ? 0 : (cap_l > 1024 ? 1024 : (int)cap_l);

    // zero cursor + loss_part + sumsFB (contiguous prefix)
    hipMemsetAsync(d_ws, 0, (size_t)(1024 + 1024 + KK * DD) * 4, stream);

    vq_prep<<<KK / 16, 64, 0, stream>>>(E, Efrag, esq);
    vq_main<<<NN / BM, 256, 0, stream>>>(X, E, Efrag, esq, o_arg, o_mind, o_Z,
                                         cursor, rowlist, sumsFB, loss_part, cap);
    vq_cs<<<1, 1024, 0, stream>>>(cluster_sizes, cursor, loss_part, o_cs, o_loss);
    vq_sum_ema<<<KK, 256, 0, stream>>>(X, rowlist, cursor, sumsFB, o_cs,
                                       moving_avg, o_ma, o_enew, cap);
}

// Round 7
// 230.217 us; speedup vs baseline: 1.7369x; 1.0483x over previous
//
#include <hip/hip_runtime.h>
#include <math.h>

// Problem constants (fixed by the reference)
#define NN 131072
#define KK 1024
#define DD 64
#define GAMMA 0.99f
#define ALPHA 1e-9f
#define BETA 0.25f

typedef float f32x4 __attribute__((ext_vector_type(4)));
typedef short bf16x8 __attribute__((ext_vector_type(8)));

__device__ __constant__ float OMG = (float)(1.0 - 0.99);

// split fp32 -> hi (truncated bf16) + lo (RNE bf16 of residual)
__device__ __forceinline__ void split_bf16(float v, unsigned short& h, unsigned short& l) {
    unsigned int b = __float_as_uint(v);
    unsigned int hb = b & 0xFFFF0000u;
    h = (unsigned short)(hb >> 16);
    float r = v - __uint_as_float(hb);
    unsigned int lb = __float_as_uint(r);
    lb += 0x7FFFu + ((lb >> 16) & 1u);
    l = (unsigned short)(lb >> 16);
}

// ---------------------------------------------------------------------------
// Prep: build E B-fragments in MFMA layout (hi/lo split) + esqh = -|e|^2/2.
// ---------------------------------------------------------------------------
__global__ __launch_bounds__(64)
void vq_prep(const float* __restrict__ E, float4* __restrict__ Efrag,
             float* __restrict__ esqh) {
    int nt = blockIdx.x;
    int l = threadIdx.x;
    int n = nt * 16 + (l & 15);
    int kb = (l >> 4) * 8;
    float ss = 0.f;
    #pragma unroll
    for (int ks = 0; ks < 2; ++ks) {
        const float4* xp = (const float4*)(E + (size_t)n * DD + ks * 32 + kb);
        float4 a = xp[0], b = xp[1];
        float v[8] = {a.x, a.y, a.z, a.w, b.x, b.y, b.z, b.w};
        union { float4 f; unsigned short u[8]; } H, L;
        #pragma unroll
        for (int j = 0; j < 8; ++j) {
            unsigned short hh, ll;
            split_bf16(v[j], hh, ll);
            H.u[j] = hh; L.u[j] = ll;
            ss = fmaf(v[j], v[j], ss);
        }
        int fid = nt * 4 + ks * 2;
        Efrag[(size_t)(fid + 0) * 64 + l] = H.f;
        Efrag[(size_t)(fid + 1) * 64 + l] = L.f;
    }
    ss += __shfl_xor(ss, 16, 64);
    ss += __shfl_xor(ss, 32, 64);
    if (l < 16) esqh[nt * 16 + l] = -0.5f * ss;   // MFMA C-init: score = d - esq/2
}

// ---------------------------------------------------------------------------
// Main: split-bf16 MFMA distance GEMM + argmax(score) + light epilogue.
// BM=64, 4 waves: rg=w&1 (2 row-groups of 32), cg=w>>1 (2 col-groups of 512).
// Per wave: 2 m-tiles -> 32 A-frag VGPRs + 8 acc, targeting the <=128-reg
// occupancy tier (4 waves/SIMD; R6 was stuck at 2 with 4 m-tiles).
// acc init = -esq/2 => final acc = dot - esq/2; argmin dist == argmax acc.
// ---------------------------------------------------------------------------
#define BM 64

__global__ __launch_bounds__(256, 2)
void vq_main(const float* __restrict__ X, const float* __restrict__ E,
             const float4* __restrict__ Efrag, const float* __restrict__ esqh,
             float* __restrict__ argf, float* __restrict__ mind,
             float* __restrict__ Z, int* __restrict__ cursor,
             int* __restrict__ rowlist, float* __restrict__ sumsFB,
             float* __restrict__ loss_part, int cap) {
    __shared__ float redv[128];   // 64 rows x 2 col-groups
    __shared__ int redi[128];
    __shared__ int bidx[64];
    __shared__ float bsc[64];
    __shared__ float xsqs[64];
    __shared__ int fbflag[64];

    int tid = threadIdx.x;
    int lane = tid & 63, w = tid >> 6;
    int rg = w & 1, cg = w >> 1;
    int lc = lane & 15, lq = lane >> 4;

    size_t bb = (size_t)blockIdx.x * BM;
    size_t R0 = bb + rg * 32;

    // A fragments: 2 m-tiles x 2 k-steps, hi+lo (32 VGPRs) + exact xsq
    bf16x8 ah[2][2], al[2][2];
    #pragma unroll
    for (int mt = 0; mt < 2; ++mt) {
        float xq = 0.f;
        #pragma unroll
        for (int ks = 0; ks < 2; ++ks) {
            const float4* xp =
                (const float4*)(X + (R0 + mt * 16 + lc) * DD + ks * 32 + lq * 8);
            float4 x0 = xp[0], x1 = xp[1];
            float v[8] = {x0.x, x0.y, x0.z, x0.w, x1.x, x1.y, x1.z, x1.w};
            union { bf16x8 s; unsigned short u[8]; } H, L;
            #pragma unroll
            for (int j = 0; j < 8; ++j) {
                unsigned short hh, ll;
                split_bf16(v[j], hh, ll);
                H.u[j] = hh; L.u[j] = ll;
                xq = fmaf(v[j], v[j], xq);
            }
            ah[mt][ks] = H.s;
            al[mt][ks] = L.s;
        }
        xq += __shfl_xor(xq, 16, 64);
        xq += __shfl_xor(xq, 32, 64);
        if (lane < 16) xsqs[rg * 32 + mt * 16 + lane] = xq;
    }

    float bestv[2][4];
    int besti[2][4];
    #pragma unroll
    for (int mt = 0; mt < 2; ++mt)
        #pragma unroll
        for (int r = 0; r < 4; ++r) { bestv[mt][r] = -3.402823466e38f; besti[mt][r] = 0; }

    const float4* bp = Efrag + (size_t)(cg * 32) * 256 + lane;
    const float* ep = esqh + cg * 512 + lc;

    float4 nb0 = bp[0], nb1 = bp[64], nb2 = bp[128], nb3 = bp[192];
    float en = ep[0];

    for (int nt = 0; nt < 32; ++nt) {
        float4 cb0 = nb0, cb1 = nb1, cb2 = nb2, cb3 = nb3;
        float ec = en;
        if (nt < 31) {
            const float4* q = bp + (size_t)(nt + 1) * 256;
            nb0 = q[0]; nb1 = q[64]; nb2 = q[128]; nb3 = q[192];
            en = ep[(nt + 1) * 16];
        }
        union { float4 f; bf16x8 s; } u0, u1, u2, u3;
        u0.f = cb0; u1.f = cb1; u2.f = cb2; u3.f = cb3;
        bf16x8 bh0 = u0.s, bl0 = u1.s, bh1 = u2.s, bl1 = u3.s;

        f32x4 acc[2];
        #pragma unroll
        for (int mt = 0; mt < 2; ++mt) acc[mt] = (f32x4){ec, ec, ec, ec};

        #pragma unroll
        for (int mt = 0; mt < 2; ++mt)
            acc[mt] = __builtin_amdgcn_mfma_f32_16x16x32_bf16(ah[mt][0], bh0, acc[mt], 0, 0, 0);
        #pragma unroll
        for (int mt = 0; mt < 2; ++mt)
            acc[mt] = __builtin_amdgcn_mfma_f32_16x16x32_bf16(ah[mt][1], bh1, acc[mt], 0, 0, 0);
        #pragma unroll
        for (int mt = 0; mt < 2; ++mt)
            acc[mt] = __builtin_amdgcn_mfma_f32_16x16x32_bf16(ah[mt][0], bl0, acc[mt], 0, 0, 0);
        #pragma unroll
        for (int mt = 0; mt < 2; ++mt)
            acc[mt] = __builtin_amdgcn_mfma_f32_16x16x32_bf16(ah[mt][1], bl1, acc[mt], 0, 0, 0);
        #pragma unroll
        for (int mt = 0; mt < 2; ++mt)
            acc[mt] = __builtin_amdgcn_mfma_f32_16x16x32_bf16(al[mt][0], bh0, acc[mt], 0, 0, 0);
        #pragma unroll
        for (int mt = 0; mt < 2; ++mt)
            acc[mt] = __builtin_amdgcn_mfma_f32_16x16x32_bf16(al[mt][1], bh1, acc[mt], 0, 0, 0);

        int n = cg * 512 + nt * 16 + lc;
        #pragma unroll
        for (int mt = 0; mt < 2; ++mt) {
            #pragma unroll
            for (int r = 0; r < 4; ++r) {
                float sc = acc[mt][r];
                if (sc > bestv[mt][r]) { bestv[mt][r] = sc; besti[mt][r] = n; }
            }
        }
    }

    // reduce across the 16 lanes holding one row (max score, low-index ties)
    #pragma unroll
    for (int off = 1; off <= 8; off <<= 1) {
        #pragma unroll
        for (int mt = 0; mt < 2; ++mt) {
            #pragma unroll
            for (int r = 0; r < 4; ++r) {
                float ov = __shfl_xor(bestv[mt][r], off, 64);
                int oi = __shfl_xor(besti[mt][r], off, 64);
                if (ov > bestv[mt][r] || (ov == bestv[mt][r] && oi < besti[mt][r])) {
                    bestv[mt][r] = ov; besti[mt][r] = oi;
                }
            }
        }
    }
    if (lc == 0) {
        #pragma unroll
        for (int mt = 0; mt < 2; ++mt)
            #pragma unroll
            for (int r = 0; r < 4; ++r) {
                int row = rg * 32 + mt * 16 + lq * 4 + r;
                redv[row * 2 + cg] = bestv[mt][r];
                redi[row * 2 + cg] = besti[mt][r];
            }
    }
    __syncthreads();
    if (tid < 64) {
        float v0 = redv[tid * 2], v1 = redv[tid * 2 + 1];
        int i0 = redi[tid * 2], i1 = redi[tid * 2 + 1];
        int pick = (v1 > v0 || (v1 == v0 && i1 < i0));
        bidx[tid] = pick ? i1 : i0;
        bsc[tid] = pick ? v1 : v0;
    }
    __syncthreads();

    // Phase B: one row per lane of wave 0 -> 64 concurrent cursor atomics
    if (tid < 64) {
        int row = tid;
        int bi = bidx[row];
        size_t grow = bb + row;
        float md = fmaf(-2.f, bsc[row], xsqs[row]);  // dist = xsq - 2*best
        mind[grow] = md;
        argf[grow] = (float)bi;
        int pos = atomicAdd(&cursor[bi], 1);
        if (pos < cap) {
            rowlist[(size_t)bi * cap + pos] = (int)grow;
            fbflag[row] = 0;
        } else {
            fbflag[row] = 1;
        }
        #pragma unroll
        for (int m = 32; m; m >>= 1) md += __shfl_xor(md, m, 64);
        if (tid == 0) atomicAdd(&loss_part[blockIdx.x & 1023], md);
    }
    __syncthreads();

    // Phase C: Z = E[argmin] gather stream
    #pragma unroll 4
    for (int it = 0; it < 16; ++it) {
        int row = w * 16 + it;
        int bi = bidx[row];
        size_t grow = bb + row;
        float e = E[(size_t)bi * DD + lane];
        Z[grow * DD + lane] = e;
        if (fbflag[row]) {
            float x = X[grow * DD + lane];
            atomicAdd(&sumsFB[(size_t)bi * DD + lane], x);
        }
    }
}

// ---------------------------------------------------------------------------
// Segment sum + cs + loss + ma/E_new, fully fused. One block per code k.
// Each block re-reduces the tiny cursor/cluster_sizes arrays (8 KB, L2-hot)
// to get the cs normalizer; block 0 also finalizes the loss.
// ---------------------------------------------------------------------------
__global__ __launch_bounds__(256)
void vq_sum_ema(const float* __restrict__ X, const int* __restrict__ rowlist,
                const int* __restrict__ cursor, const float* __restrict__ sumsFB,
                const float* __restrict__ cluster_sizes,
                const float* __restrict__ loss_part, const float* __restrict__ mavg,
                float* __restrict__ o_ma, float* __restrict__ o_enew,
                float* __restrict__ o_cs, float* __restrict__ o_loss, int cap) {
    __shared__ float part[4][64];
    __shared__ float redt[4];
    int k = blockIdx.x;
    int lane = threadIdx.x & 63, w = threadIdx.x >> 6;

    // total = sum_j gamma*cluster_sizes[j] + (1-gamma)*counts[j]
    float t = 0.f;
    for (int j = threadIdx.x; j < KK; j += 256)
        t += GAMMA * cluster_sizes[j] + OMG * (float)cursor[j];
    #pragma unroll
    for (int m = 32; m; m >>= 1) t += __shfl_xor(t, m, 64);
    if (lane == 0) redt[w] = t;
    __syncthreads();
    float total = redt[0] + redt[1] + redt[2] + redt[3];

    float csr = GAMMA * cluster_sizes[k] + OMG * (float)cursor[k];
    float cs = (csr + ALPHA) / (1.0f + (ALPHA * (float)KK) / total);
    if (threadIdx.x == 0) o_cs[k] = cs;

    if (k == 0) {   // loss finalize
        float t2 = 0.f;
        for (int j = threadIdx.x; j < 1024; j += 256) t2 += loss_part[j];
        #pragma unroll
        for (int m = 32; m; m >>= 1) t2 += __shfl_xor(t2, m, 64);
        if (lane == 0) redt[w] = t2;
        __syncthreads();
        if (threadIdx.x == 0) {
            float l = redt[0] + redt[1] + redt[2] + redt[3];
            o_loss[0] = BETA * (l / (float)NN);
        }
    }

    // segment sum over this code's rows (atomic-free)
    int cnt = cursor[k];
    int nr = cnt < cap ? cnt : cap;
    const int* rl = rowlist + (size_t)k * cap;
    float acc = 0.f;
    #pragma unroll 4
    for (int i = w; i < nr; i += 4) {
        int r = rl[i];
        acc += X[(size_t)r * DD + lane];
    }
    part[w][lane] = acc;
    __syncthreads();
    if (w == 0) {
        float s = part[0][lane] + part[1][lane] + part[2][lane] + part[3][lane]
                + sumsFB[(size_t)k * DD + lane];
        float ma = GAMMA * mavg[(size_t)k * DD + lane] + OMG * s;
        o_ma[(size_t)k * DD + lane] = ma;
        o_enew[(size_t)k * DD + lane] = ma / cs;
    }
}

// ---------------------------------------------------------------------------
extern "C" void kernel_launch(void* const* d_in, const int* in_sizes, int n_in,
                              void* d_out, int out_size, void* d_ws, size_t ws_size,
                              hipStream_t stream) {
    const float* X = (const float*)d_in[0];
    const float* E = (const float*)d_in[1];
    const float* cluster_sizes = (const float*)d_in[2];
    const float* moving_avg = (const float*)d_in[3];

    // Output layout: Z[N*D], loss[1], argmins[N], min_dist[N],
    //                E_new[K*D], cs[K], ma[K*D]
    float* out = (float*)d_out;
    float* o_Z = out;
    float* o_loss = o_Z + (size_t)NN * DD;
    float* o_arg = o_loss + 1;
    float* o_mind = o_arg + NN;
    float* o_enew = o_mind + NN;
    float* o_cs = o_enew + (size_t)KK * DD;
    float* o_ma = o_cs + KK;

    // Workspace (4B units):
    // [cursor 1024 i32][loss_part 1024 f][sumsFB 65536 f][esqh 1024 f]
    // [Efrag 65536 f][rowlist K*cap i32]
    int* cursor = (int*)d_ws;
    float* loss_part = (float*)d_ws + 1024;
    float* sumsFB = loss_part + 1024;
    float* esqh = sumsFB + (size_t)KK * DD;
    float4* Efrag = (float4*)(esqh + KK);
    int* rowlist = (int*)(esqh + KK + (size_t)KK * DD);

    size_t base_bytes = (size_t)(1024 + 1024 + KK * DD + KK + KK * DD) * 4;
    long cap_l = ((long)ws_size - (long)base_bytes) / (long)(KK * sizeof(int));
    int cap = cap_l < 0 ? 0 : (cap_l > 1024 ? 1024 : (int)cap_l);

    // zero cursor + loss_part + sumsFB (contiguous prefix)
    hipMemsetAsync(d_ws, 0, (size_t)(1024 + 1024 + KK * DD) * 4, stream);

    vq_prep<<<KK / 16, 64, 0, stream>>>(E, Efrag, esqh);
    vq_main<<<NN / BM, 256, 0, stream>>>(X, E, Efrag, esqh, o_arg, o_mind, o_Z,
                                         cursor, rowlist, sumsFB, loss_part, cap);
    vq_sum_ema<<<KK, 256, 0, stream>>>(X, rowlist, cursor, sumsFB, cluster_sizes,
                                       loss_part, moving_avg, o_ma, o_enew,
                                       o_cs, o_loss, cap);
}

// Round 8
// 206.636 us; speedup vs baseline: 1.9351x; 1.1141x over previous
//
#include <hip/hip_runtime.h>
#include <math.h>

// Problem constants (fixed by the reference)
#define NN 131072
#define KK 1024
#define DD 64
#define GAMMA 0.99f
#define ALPHA 1e-9f
#define BETA 0.25f

typedef float f32x4 __attribute__((ext_vector_type(4)));
typedef short bf16x8 __attribute__((ext_vector_type(8)));

__device__ __constant__ float OMG = (float)(1.0 - 0.99);

// split fp32 -> hi (truncated bf16) + lo (RNE bf16 of residual)
__device__ __forceinline__ void split_bf16(float v, unsigned short& h, unsigned short& l) {
    unsigned int b = __float_as_uint(v);
    unsigned int hb = b & 0xFFFF0000u;
    h = (unsigned short)(hb >> 16);
    float r = v - __uint_as_float(hb);
    unsigned int lb = __float_as_uint(r);
    lb += 0x7FFFu + ((lb >> 16) & 1u);
    l = (unsigned short)(lb >> 16);
}

// ---------------------------------------------------------------------------
// Prep: build E B-fragments in MFMA layout (hi/lo split) + esqh = -|e|^2/2.
// ---------------------------------------------------------------------------
__global__ __launch_bounds__(64)
void vq_prep(const float* __restrict__ E, float4* __restrict__ Efrag,
             float* __restrict__ esqh) {
    int nt = blockIdx.x;
    int l = threadIdx.x;
    int n = nt * 16 + (l & 15);
    int kb = (l >> 4) * 8;
    float ss = 0.f;
    #pragma unroll
    for (int ks = 0; ks < 2; ++ks) {
        const float4* xp = (const float4*)(E + (size_t)n * DD + ks * 32 + kb);
        float4 a = xp[0], b = xp[1];
        float v[8] = {a.x, a.y, a.z, a.w, b.x, b.y, b.z, b.w};
        union { float4 f; unsigned short u[8]; } H, L;
        #pragma unroll
        for (int j = 0; j < 8; ++j) {
            unsigned short hh, ll;
            split_bf16(v[j], hh, ll);
            H.u[j] = hh; L.u[j] = ll;
            ss = fmaf(v[j], v[j], ss);
        }
        int fid = nt * 4 + ks * 2;
        Efrag[(size_t)(fid + 0) * 64 + l] = H.f;
        Efrag[(size_t)(fid + 1) * 64 + l] = L.f;
    }
    ss += __shfl_xor(ss, 16, 64);
    ss += __shfl_xor(ss, 32, 64);
    if (l < 16) esqh[nt * 16 + l] = -0.5f * ss;   // MFMA C-init: score = d - esq/2
}

// ---------------------------------------------------------------------------
// Main: split-bf16 MFMA distance GEMM + argmax(score) + light epilogue.
// BM=64, 4 waves: rg=w&1 (32 rows each), cg=w>>1 (512 cols each).
// De-phased sweep: block-dependent start offset in the circular nt order so
// the 256 CUs don't hammer the same Efrag lines/L2 banks in lockstep.
// Depth-2 zero-copy prefetch (two named buffer sets, unroll 2).
// acc init = -esq/2 => final acc = dot - esq/2; argmin dist == argmax acc.
// ---------------------------------------------------------------------------
#define BM 64

__global__ __launch_bounds__(256, 2)
void vq_main(const float* __restrict__ X, const float* __restrict__ E,
             const float4* __restrict__ Efrag, const float* __restrict__ esqh,
             float* __restrict__ argf, float* __restrict__ mind,
             float* __restrict__ Z, int* __restrict__ cursor,
             int* __restrict__ rowlist, float* __restrict__ sumsFB,
             float* __restrict__ loss_part, int cap) {
    __shared__ float redv[128];   // 64 rows x 2 col-groups
    __shared__ int redi[128];
    __shared__ int bidx[64];
    __shared__ float bsc[64];
    __shared__ float xsqs[64];
    __shared__ int fbflag[64];

    int tid = threadIdx.x;
    int lane = tid & 63, w = tid >> 6;
    int rg = w & 1, cg = w >> 1;
    int lc = lane & 15, lq = lane >> 4;

    size_t bb = (size_t)blockIdx.x * BM;
    size_t R0 = bb + rg * 32;

    // A fragments: 2 m-tiles x 2 k-steps, hi+lo (32 VGPRs) + exact xsq
    bf16x8 ah[2][2], al[2][2];
    #pragma unroll
    for (int mt = 0; mt < 2; ++mt) {
        float xq = 0.f;
        #pragma unroll
        for (int ks = 0; ks < 2; ++ks) {
            const float4* xp =
                (const float4*)(X + (R0 + mt * 16 + lc) * DD + ks * 32 + lq * 8);
            float4 x0 = xp[0], x1 = xp[1];
            float v[8] = {x0.x, x0.y, x0.z, x0.w, x1.x, x1.y, x1.z, x1.w};
            union { bf16x8 s; unsigned short u[8]; } H, L;
            #pragma unroll
            for (int j = 0; j < 8; ++j) {
                unsigned short hh, ll;
                split_bf16(v[j], hh, ll);
                H.u[j] = hh; L.u[j] = ll;
                xq = fmaf(v[j], v[j], xq);
            }
            ah[mt][ks] = H.s;
            al[mt][ks] = L.s;
        }
        xq += __shfl_xor(xq, 16, 64);
        xq += __shfl_xor(xq, 32, 64);
        if (lane < 16) xsqs[rg * 32 + mt * 16 + lane] = xq;
    }

    float bestv[2][4];
    int besti[2][4];
    #pragma unroll
    for (int mt = 0; mt < 2; ++mt)
        #pragma unroll
        for (int r = 0; r < 4; ++r) { bestv[mt][r] = -3.402823466e38f; besti[mt][r] = 0; }

    const float4* bp = Efrag + (size_t)(cg * 32) * 256 + lane;
    const float* ep = esqh + cg * 512 + lc;

    // de-phase: blocks on the same XCD (consecutive blockIdx>>3) get
    // consecutive start offsets in the circular col-tile order
    int st = (blockIdx.x >> 3) & 31;

    // depth-2 prefetch, two named buffer sets (no copy chain)
    int p0 = st;               // logical i=0
    int p1 = (st + 1) & 31;    // logical i=1
    const float4* q0 = bp + (size_t)p0 * 256;
    const float4* q1 = bp + (size_t)p1 * 256;
    float4 na0 = q0[0], na1 = q0[64], na2 = q0[128], na3 = q0[192];
    float ea = ep[p0 * 16];
    float4 mb0 = q1[0], mb1 = q1[64], mb2 = q1[128], mb3 = q1[192];
    float eb = ep[p1 * 16];

    for (int i = 0; i < 32; i += 2) {
        // ---- even sub-iter: consume set A (logical i), prefetch i+2 -> A
        {
            int ntp = (i + st) & 31;
            union { float4 f; bf16x8 s; } u0, u1, u2, u3;
            u0.f = na0; u1.f = na1; u2.f = na2; u3.f = na3;
            float ec = ea;
            if (i + 2 < 32) {
                int np = (i + 2 + st) & 31;
                const float4* q = bp + (size_t)np * 256;
                na0 = q[0]; na1 = q[64]; na2 = q[128]; na3 = q[192];
                ea = ep[np * 16];
            }
            f32x4 acc[2];
            #pragma unroll
            for (int mt = 0; mt < 2; ++mt) acc[mt] = (f32x4){ec, ec, ec, ec};
            #pragma unroll
            for (int mt = 0; mt < 2; ++mt)
                acc[mt] = __builtin_amdgcn_mfma_f32_16x16x32_bf16(ah[mt][0], u0.s, acc[mt], 0, 0, 0);
            #pragma unroll
            for (int mt = 0; mt < 2; ++mt)
                acc[mt] = __builtin_amdgcn_mfma_f32_16x16x32_bf16(ah[mt][1], u2.s, acc[mt], 0, 0, 0);
            #pragma unroll
            for (int mt = 0; mt < 2; ++mt)
                acc[mt] = __builtin_amdgcn_mfma_f32_16x16x32_bf16(ah[mt][0], u1.s, acc[mt], 0, 0, 0);
            #pragma unroll
            for (int mt = 0; mt < 2; ++mt)
                acc[mt] = __builtin_amdgcn_mfma_f32_16x16x32_bf16(ah[mt][1], u3.s, acc[mt], 0, 0, 0);
            #pragma unroll
            for (int mt = 0; mt < 2; ++mt)
                acc[mt] = __builtin_amdgcn_mfma_f32_16x16x32_bf16(al[mt][0], u0.s, acc[mt], 0, 0, 0);
            #pragma unroll
            for (int mt = 0; mt < 2; ++mt)
                acc[mt] = __builtin_amdgcn_mfma_f32_16x16x32_bf16(al[mt][1], u2.s, acc[mt], 0, 0, 0);
            int n = cg * 512 + ntp * 16 + lc;
            #pragma unroll
            for (int mt = 0; mt < 2; ++mt)
                #pragma unroll
                for (int r = 0; r < 4; ++r) {
                    float sc = acc[mt][r];
                    if (sc > bestv[mt][r]) { bestv[mt][r] = sc; besti[mt][r] = n; }
                }
        }
        // ---- odd sub-iter: consume set B (logical i+1), prefetch i+3 -> B
        {
            int ntp = (i + 1 + st) & 31;
            union { float4 f; bf16x8 s; } u0, u1, u2, u3;
            u0.f = mb0; u1.f = mb1; u2.f = mb2; u3.f = mb3;
            float ec = eb;
            if (i + 3 < 32) {
                int np = (i + 3 + st) & 31;
                const float4* q = bp + (size_t)np * 256;
                mb0 = q[0]; mb1 = q[64]; mb2 = q[128]; mb3 = q[192];
                eb = ep[np * 16];
            }
            f32x4 acc[2];
            #pragma unroll
            for (int mt = 0; mt < 2; ++mt) acc[mt] = (f32x4){ec, ec, ec, ec};
            #pragma unroll
            for (int mt = 0; mt < 2; ++mt)
                acc[mt] = __builtin_amdgcn_mfma_f32_16x16x32_bf16(ah[mt][0], u0.s, acc[mt], 0, 0, 0);
            #pragma unroll
            for (int mt = 0; mt < 2; ++mt)
                acc[mt] = __builtin_amdgcn_mfma_f32_16x16x32_bf16(ah[mt][1], u2.s, acc[mt], 0, 0, 0);
            #pragma unroll
            for (int mt = 0; mt < 2; ++mt)
                acc[mt] = __builtin_amdgcn_mfma_f32_16x16x32_bf16(ah[mt][0], u1.s, acc[mt], 0, 0, 0);
            #pragma unroll
            for (int mt = 0; mt < 2; ++mt)
                acc[mt] = __builtin_amdgcn_mfma_f32_16x16x32_bf16(ah[mt][1], u3.s, acc[mt], 0, 0, 0);
            #pragma unroll
            for (int mt = 0; mt < 2; ++mt)
                acc[mt] = __builtin_amdgcn_mfma_f32_16x16x32_bf16(al[mt][0], u0.s, acc[mt], 0, 0, 0);
            #pragma unroll
            for (int mt = 0; mt < 2; ++mt)
                acc[mt] = __builtin_amdgcn_mfma_f32_16x16x32_bf16(al[mt][1], u2.s, acc[mt], 0, 0, 0);
            int n = cg * 512 + ntp * 16 + lc;
            #pragma unroll
            for (int mt = 0; mt < 2; ++mt)
                #pragma unroll
                for (int r = 0; r < 4; ++r) {
                    float sc = acc[mt][r];
                    if (sc > bestv[mt][r]) { bestv[mt][r] = sc; besti[mt][r] = n; }
                }
        }
    }

    // reduce across the 16 lanes holding one row (max score, low-index ties)
    #pragma unroll
    for (int off = 1; off <= 8; off <<= 1) {
        #pragma unroll
        for (int mt = 0; mt < 2; ++mt) {
            #pragma unroll
            for (int r = 0; r < 4; ++r) {
                float ov = __shfl_xor(bestv[mt][r], off, 64);
                int oi = __shfl_xor(besti[mt][r], off, 64);
                if (ov > bestv[mt][r] || (ov == bestv[mt][r] && oi < besti[mt][r])) {
                    bestv[mt][r] = ov; besti[mt][r] = oi;
                }
            }
        }
    }
    if (lc == 0) {
        #pragma unroll
        for (int mt = 0; mt < 2; ++mt)
            #pragma unroll
            for (int r = 0; r < 4; ++r) {
                int row = rg * 32 + mt * 16 + lq * 4 + r;
                redv[row * 2 + cg] = bestv[mt][r];
                redi[row * 2 + cg] = besti[mt][r];
            }
    }
    __syncthreads();
    if (tid < 64) {
        float v0 = redv[tid * 2], v1 = redv[tid * 2 + 1];
        int i0 = redi[tid * 2], i1 = redi[tid * 2 + 1];
        int pick = (v1 > v0 || (v1 == v0 && i1 < i0));
        bidx[tid] = pick ? i1 : i0;
        bsc[tid] = pick ? v1 : v0;
    }
    __syncthreads();

    // Phase B: one row per lane of wave 0 -> 64 concurrent cursor atomics
    if (tid < 64) {
        int row = tid;
        int bi = bidx[row];
        size_t grow = bb + row;
        float md = fmaf(-2.f, bsc[row], xsqs[row]);  // dist = xsq - 2*best
        mind[grow] = md;
        argf[grow] = (float)bi;
        int pos = atomicAdd(&cursor[bi], 1);
        if (pos < cap) {
            rowlist[(size_t)bi * cap + pos] = (int)grow;
            fbflag[row] = 0;
        } else {
            fbflag[row] = 1;
        }
        #pragma unroll
        for (int m = 32; m; m >>= 1) md += __shfl_xor(md, m, 64);
        if (tid == 0) atomicAdd(&loss_part[blockIdx.x & 1023], md);
    }
    __syncthreads();

    // Phase C: Z = E[argmin] gather stream
    #pragma unroll 4
    for (int it = 0; it < 16; ++it) {
        int row = w * 16 + it;
        int bi = bidx[row];
        size_t grow = bb + row;
        float e = E[(size_t)bi * DD + lane];
        Z[grow * DD + lane] = e;
        if (fbflag[row]) {
            float x = X[grow * DD + lane];
            atomicAdd(&sumsFB[(size_t)bi * DD + lane], x);
        }
    }
}

// ---------------------------------------------------------------------------
// Segment sum + cs + loss + ma/E_new, fully fused. One 1024-thread block per
// code k: 16 waves split the row list (4x shorter worst-cluster chain).
// ---------------------------------------------------------------------------
__global__ __launch_bounds__(1024)
void vq_sum_ema(const float* __restrict__ X, const int* __restrict__ rowlist,
                const int* __restrict__ cursor, const float* __restrict__ sumsFB,
                const float* __restrict__ cluster_sizes,
                const float* __restrict__ loss_part, const float* __restrict__ mavg,
                float* __restrict__ o_ma, float* __restrict__ o_enew,
                float* __restrict__ o_cs, float* __restrict__ o_loss, int cap) {
    __shared__ float part[16][64];
    __shared__ float redt[16];
    int k = blockIdx.x;
    int lane = threadIdx.x & 63, w = threadIdx.x >> 6;

    // total = sum_j gamma*cluster_sizes[j] + (1-gamma)*counts[j]
    float t = GAMMA * cluster_sizes[threadIdx.x] + OMG * (float)cursor[threadIdx.x];
    #pragma unroll
    for (int m = 32; m; m >>= 1) t += __shfl_xor(t, m, 64);
    if (lane == 0) redt[w] = t;
    __syncthreads();
    float total = 0.f;
    #pragma unroll
    for (int j = 0; j < 16; ++j) total += redt[j];

    float csr = GAMMA * cluster_sizes[k] + OMG * (float)cursor[k];
    float cs = (csr + ALPHA) / (1.0f + (ALPHA * (float)KK) / total);
    if (threadIdx.x == 0) o_cs[k] = cs;

    if (k == 0) {   // loss finalize
        __syncthreads();
        float t2 = loss_part[threadIdx.x];
        #pragma unroll
        for (int m = 32; m; m >>= 1) t2 += __shfl_xor(t2, m, 64);
        if (lane == 0) redt[w] = t2;
        __syncthreads();
        if (threadIdx.x == 0) {
            float l = 0.f;
            #pragma unroll
            for (int j = 0; j < 16; ++j) l += redt[j];
            o_loss[0] = BETA * (l / (float)NN);
        }
    }

    // segment sum over this code's rows (atomic-free), 16 waves
    int cnt = cursor[k];
    int nr = cnt < cap ? cnt : cap;
    const int* rl = rowlist + (size_t)k * cap;
    float acc = 0.f;
    #pragma unroll 4
    for (int i = w; i < nr; i += 16) {
        int r = rl[i];
        acc += X[(size_t)r * DD + lane];
    }
    part[w][lane] = acc;
    __syncthreads();
    if (w == 0) {
        float s = sumsFB[(size_t)k * DD + lane];
        #pragma unroll
        for (int j = 0; j < 16; ++j) s += part[j][lane];
        float ma = GAMMA * mavg[(size_t)k * DD + lane] + OMG * s;
        o_ma[(size_t)k * DD + lane] = ma;
        o_enew[(size_t)k * DD + lane] = ma / cs;
    }
}

// ---------------------------------------------------------------------------
extern "C" void kernel_launch(void* const* d_in, const int* in_sizes, int n_in,
                              void* d_out, int out_size, void* d_ws, size_t ws_size,
                              hipStream_t stream) {
    const float* X = (const float*)d_in[0];
    const float* E = (const float*)d_in[1];
    const float* cluster_sizes = (const float*)d_in[2];
    const float* moving_avg = (const float*)d_in[3];

    // Output layout: Z[N*D], loss[1], argmins[N], min_dist[N],
    //                E_new[K*D], cs[K], ma[K*D]
    float* out = (float*)d_out;
    float* o_Z = out;
    float* o_loss = o_Z + (size_t)NN * DD;
    float* o_arg = o_loss + 1;
    float* o_mind = o_arg + NN;
    float* o_enew = o_mind + NN;
    float* o_cs = o_enew + (size_t)KK * DD;
    float* o_ma = o_cs + KK;

    // Workspace (4B units):
    // [cursor 1024 i32][loss_part 1024 f][sumsFB 65536 f][esqh 1024 f]
    // [Efrag 65536 f][rowlist K*cap i32]
    int* cursor = (int*)d_ws;
    float* loss_part = (float*)d_ws + 1024;
    float* sumsFB = loss_part + 1024;
    float* esqh = sumsFB + (size_t)KK * DD;
    float4* Efrag = (float4*)(esqh + KK);
    int* rowlist = (int*)(esqh + KK + (size_t)KK * DD);

    size_t base_bytes = (size_t)(1024 + 1024 + KK * DD + KK + KK * DD) * 4;
    long cap_l = ((long)ws_size - (long)base_bytes) / (long)(KK * sizeof(int));
    int cap = cap_l < 0 ? 0 : (cap_l > 1024 ? 1024 : (int)cap_l);

    // zero cursor + loss_part + sumsFB (contiguous prefix)
    hipMemsetAsync(d_ws, 0, (size_t)(1024 + 1024 + KK * DD) * 4, stream);

    vq_prep<<<KK / 16, 64, 0, stream>>>(E, Efrag, esqh);
    vq_main<<<NN / BM, 256, 0, stream>>>(X, E, Efrag, esqh, o_arg, o_mind, o_Z,
                                         cursor, rowlist, sumsFB, loss_part, cap);
    vq_sum_ema<<<KK, 1024, 0, stream>>>(X, rowlist, cursor, sumsFB, cluster_sizes,
                                        loss_part, moving_avg, o_ma, o_enew,
                                        o_cs, o_loss, cap);
}